// Round 9
// baseline (2785.830 us; speedup 1.0000x reference)
//
// moe_fused v7: 16 waves (1024 thr) + waves_per_eu(4,4) pin + lean LN epilogue
// = round-5 concurrency experiment re-run without the register-spill confound.
#include <hip/hip_runtime.h>

#define N_TOK 131072
#define D_INP 256
#define D_HID 512
#define D_OUTP 256
#define NEXP 8

typedef unsigned short u16;
using short8  = __attribute__((ext_vector_type(8))) short;
using floatx4 = __attribute__((ext_vector_type(4))) float;

#define WAITVM(N) asm volatile("s_waitcnt vmcnt(" #N ")" ::: "memory")
#define WAITLGKM0 asm volatile("s_waitcnt lgkmcnt(0)" ::: "memory")
#define BAR() __builtin_amdgcn_s_barrier()

static __device__ __forceinline__ u16 f2bf(float f) {
  unsigned u = __float_as_uint(f);
  u = (u + 0x7fffu + ((u >> 16) & 1u)) >> 16;   // round-to-nearest-even
  return (u16)u;
}
static __device__ __forceinline__ float bf2f(u16 u) {
  return __uint_as_float(((unsigned)u) << 16);
}
static __device__ __forceinline__ float gelu_exact(float v) {
  return 0.5f * v * (1.0f + erff(v * 0.70710678118654752f));
}
// async global->LDS, 16B per lane; dest must be wave-uniform base + lane*16
static __device__ __forceinline__ void gload16(const void* g, void* l) {
  __builtin_amdgcn_global_load_lds(
      (const __attribute__((address_space(1))) void*)g,
      (__attribute__((address_space(3))) void*)l, 16, 0, 0);
}
// stage a 32KB weight tile with 1024 threads (2 VMEM instr / thread)
static __device__ __forceinline__ void stage32(const u16* wsrc, u16* dst, int t) {
#pragma unroll
  for (int i = 0; i < 2; ++i) {
    int idx = t + i * 1024;
    gload16(wsrc + (size_t)idx * 8, dst + (size_t)idx * 8);
  }
}
// stage a 16KB weight tile with 1024 threads (1 VMEM instr / thread)
static __device__ __forceinline__ void stage16(const u16* wsrc, u16* dst, int t) {
  gload16(wsrc + (size_t)t * 8, dst + (size_t)t * 8);
}

// ---------------------------------------------------------------------------
// Gating: one wave per token. logits = tanh(x@gw1) @ gw2 ; softmax ; top-2 ;
// renormalize. Writes (e1,e2) + (w1,w2) per token. Also casts x -> bf16.
// ---------------------------------------------------------------------------
__global__ __launch_bounds__(256) void gate_cast(
    const float* __restrict__ x, const float* __restrict__ gw1,
    const float* __restrict__ gw2, u16* __restrict__ xb,
    int2* __restrict__ tope, float2* __restrict__ wts) {
  const int lane  = threadIdx.x & 63;
  const int token = blockIdx.x * 4 + (threadIdx.x >> 6);

  const float4 v = ((const float4*)(x + (size_t)token * D_INP))[lane];

  ushort4 b4;
  b4.x = f2bf(v.x); b4.y = f2bf(v.y); b4.z = f2bf(v.z); b4.w = f2bf(v.w);
  *(ushort4*)(xb + (size_t)token * D_INP + lane * 4) = b4;

  float p[16];
#pragma unroll
  for (int j = 0; j < 16; ++j) p[j] = 0.f;
  const float va[4] = {v.x, v.y, v.z, v.w};
  const int d0 = lane * 4;
#pragma unroll
  for (int r = 0; r < 4; ++r) {
    const float xr = va[r];
    const float4* g4 = (const float4*)(gw1 + (size_t)(d0 + r) * 16);
    float4 a0 = g4[0], a1 = g4[1], a2 = g4[2], a3 = g4[3];
    p[0]  += xr * a0.x; p[1]  += xr * a0.y; p[2]  += xr * a0.z; p[3]  += xr * a0.w;
    p[4]  += xr * a1.x; p[5]  += xr * a1.y; p[6]  += xr * a1.z; p[7]  += xr * a1.w;
    p[8]  += xr * a2.x; p[9]  += xr * a2.y; p[10] += xr * a2.z; p[11] += xr * a2.w;
    p[12] += xr * a3.x; p[13] += xr * a3.y; p[14] += xr * a3.z; p[15] += xr * a3.w;
  }
#pragma unroll
  for (int m = 1; m < 64; m <<= 1) {
#pragma unroll
    for (int j = 0; j < 16; ++j) p[j] += __shfl_xor(p[j], m, 64);
  }
  float tj[16];
#pragma unroll
  for (int j = 0; j < 16; ++j) tj[j] = tanhf(p[j]);

  float lg[8];
#pragma unroll
  for (int e = 0; e < 8; ++e) {
    float s = 0.f;
#pragma unroll
    for (int j = 0; j < 16; ++j) s += tj[j] * gw2[j * 8 + e];
    lg[e] = s;
  }
  float mx = lg[0];
#pragma unroll
  for (int e = 1; e < 8; ++e) mx = fmaxf(mx, lg[e]);
  float ex[8], se = 0.f;
#pragma unroll
  for (int e = 0; e < 8; ++e) { ex[e] = expf(lg[e] - mx); se += ex[e]; }
  float inv = 1.f / se;
#pragma unroll
  for (int e = 0; e < 8; ++e) ex[e] *= inv;
  int i1 = 0; float v1 = ex[0];
#pragma unroll
  for (int e = 1; e < 8; ++e) if (ex[e] > v1) { v1 = ex[e]; i1 = e; }
  int i2 = -1; float v2 = -1.f;
#pragma unroll
  for (int e = 0; e < 8; ++e) if (e != i1 && ex[e] > v2) { v2 = ex[e]; i2 = e; }
  float rs = 1.f / (v1 + v2 + 1e-12f);

  if (lane == 0) {
    tope[token] = make_int2(i1, i2);
    wts[token]  = make_float2(v1 * rs, v2 * rs);
  }
}

// ---------------------------------------------------------------------------
// Routing: count per-expert (wave-aggregated), scan (padded to 64), assign.
// ---------------------------------------------------------------------------
__global__ __launch_bounds__(256) void count_k(const int2* __restrict__ tope,
                                               int* __restrict__ counts) {
  int t = blockIdx.x * 256 + threadIdx.x;
  int lane = threadIdx.x & 63;
  int2 ee = tope[t];
#pragma unroll
  for (int e = 0; e < 8; ++e) {
    unsigned long long m1 = __ballot(ee.x == e);
    unsigned long long m2 = __ballot(ee.y == e);
    int c = __popcll(m1) + __popcll(m2);
    if (lane == 0 && c) atomicAdd(counts + e, c);
  }
}

__global__ void scan_k(const int* __restrict__ counts, int* __restrict__ off) {
  if (threadIdx.x == 0 && blockIdx.x == 0) {
    int o = 0;
    for (int e = 0; e < 8; ++e) { off[e] = o; o += (counts[e] + 63) & ~63; }
    off[8] = o;
  }
}

__global__ __launch_bounds__(256) void assign_k(
    const int2* __restrict__ tope, const int* __restrict__ off,
    int* __restrict__ cursors, int* __restrict__ perm,
    int* __restrict__ islot) {
  int t = blockIdx.x * 256 + threadIdx.x;
  int lane = threadIdx.x & 63;
  int2 ee = tope[t];
  unsigned long long lt = (lane == 63) ? 0x7fffffffffffffffULL
                                       : ((1ULL << lane) - 1ULL);
#pragma unroll
  for (int k = 0; k < 2; ++k) {
    int e = k ? ee.y : ee.x;
#pragma unroll
    for (int q = 0; q < 8; ++q) {
      unsigned long long mask = __ballot(e == q);
      if (!mask) continue;
      int leader = __ffsll((long long)mask) - 1;
      int base = 0;
      if (lane == leader) base = atomicAdd(cursors + q, __popcll(mask));
      base = __shfl(base, leader);
      if (e == q) {
        int pos = base + __popcll(mask & lt);
        int slot = off[q] + pos;
        perm[slot] = t;
        islot[t * 2 + k] = slot;
      }
    }
  }
}

// ---------------------------------------------------------------------------
// Weight prep: W[e][k][n] fp32 -> LDS-image bf16 img[e][kt][q][n][8],
// element (k = kt*32 + q*8 + j, n). Staging then = pure linear copy.
// ---------------------------------------------------------------------------
template <int NW>
__global__ __launch_bounds__(256) void wprep(const float* __restrict__ W,
                                             u16* __restrict__ img, int K) {
  const int e = blockIdx.z, kt = blockIdx.x;
  const int chunks = 4 * NW;
  const float* Wp = W + (size_t)e * K * NW;
  u16* ip = img + ((size_t)e * (K / 32) + kt) * (size_t)chunks * 8;
  for (int idx = threadIdx.x; idx < chunks; idx += 256) {
    int q = idx / NW, n = idx % NW;
    int k0 = kt * 32 + q * 8;
    u16 tmp[8];
#pragma unroll
    for (int j = 0; j < 8; ++j) tmp[j] = f2bf(Wp[(size_t)(k0 + j) * NW + n]);
    *(uint4*)(ip + (size_t)idx * 8) = *(uint4*)tmp;
  }
}

// ---------------------------------------------------------------------------
// LN+GELU epilogue, 16-wave + register-lean: no mean/rstd arrays — mu/rsd
// recomputed inline per (rt,r) in the store loop. Raw barriers + lgkmcnt
// only — never drains vmcnt (next GEMM tile-0 prefetch stays in flight).
// Wave wv covers cols [wv*32, wv*32+32). red arrays are [64 rows][16 waves].
// ---------------------------------------------------------------------------
__device__ __forceinline__ void ln_gelu_epi16(
    floatx4 (&acc)[4][2], const float* __restrict__ bias,
    const float* __restrict__ gam, const float* __restrict__ bet,
    u16* Hs, float* redS, float* redQ, int wv, int cl, int qd) {
#pragma unroll
  for (int c = 0; c < 2; ++c) {
    float bv = bias[wv * 32 + c * 16 + cl];
#pragma unroll
    for (int rt = 0; rt < 4; ++rt)
#pragma unroll
      for (int r = 0; r < 4; ++r) acc[rt][c][r] += bv;
  }
#pragma unroll
  for (int rt = 0; rt < 4; ++rt)
#pragma unroll
    for (int r = 0; r < 4; ++r) {
      float s = 0.f, q2 = 0.f;
#pragma unroll
      for (int c = 0; c < 2; ++c) { float v = acc[rt][c][r]; s += v; q2 += v * v; }
#pragma unroll
      for (int m = 1; m < 16; m <<= 1) {
        s += __shfl_xor(s, m, 64);
        q2 += __shfl_xor(q2, m, 64);
      }
      if (cl == 0) {
        int row = rt * 16 + qd * 4 + r;
        redS[row * 16 + wv] = s;
        redQ[row * 16 + wv] = q2;
      }
    }
  WAITLGKM0;
  BAR();
  float ga2[2], be2c[2];
#pragma unroll
  for (int c = 0; c < 2; ++c) {
    int col = wv * 32 + c * 16 + cl;
    ga2[c] = gam[col];
    be2c[c] = bet[col];
  }
#pragma unroll
  for (int rt = 0; rt < 4; ++rt)
#pragma unroll
    for (int r = 0; r < 4; ++r) {
      int row = rt * 16 + qd * 4 + r;
      float s = 0.f, q2 = 0.f;
#pragma unroll
      for (int w = 0; w < 16; ++w) { s += redS[row * 16 + w]; q2 += redQ[row * 16 + w]; }
      float mu = s * (1.f / 512.f);
      float rsd = rsqrtf(q2 * (1.f / 512.f) - mu * mu + 1e-5f);
#pragma unroll
      for (int c = 0; c < 2; ++c) {
        int col = wv * 32 + c * 16 + cl;
        int kt2 = col >> 5, q2i = (col >> 3) & 3, j = col & 7;
        float v = (acc[rt][c][r] - mu) * rsd * ga2[c] + be2c[c];
        Hs[(((kt2 * 4 + q2i) * 64 + row) * 8) + j] = f2bf(gelu_exact(v));
      }
    }
  WAITLGKM0;
  BAR();
}

// ---------------------------------------------------------------------------
// Fused routed expert, 16 waves (1024 thr) = 4 waves/SIMD for latency hiding.
// waves_per_eu(4,4) pins regalloc to the 128-VGPR budget (LDS caps at
// 1 block/CU anyway) -> no scratch spills (the v5 failure mode).
// Double-buffered weight pipeline, counted vmcnt (never 0 inside k-loops).
// LDS: Hs 64K (Axf alias) | WstA 32K | WstB 32K | redS 4K | redQ 4K | sTok.
// ---------------------------------------------------------------------------
__global__ __attribute__((amdgpu_waves_per_eu(4, 4)))
__launch_bounds__(1024) void moe_fused(
    const u16* __restrict__ xb, const u16* __restrict__ W1i,
    const u16* __restrict__ W2i, const u16* __restrict__ W3i,
    const float* __restrict__ b1, const float* __restrict__ g1,
    const float* __restrict__ be1, const float* __restrict__ b2,
    const float* __restrict__ g2, const float* __restrict__ be2,
    const float* __restrict__ b3, const int* __restrict__ off,
    const int* __restrict__ counts, const int* __restrict__ perm,
    u16* __restrict__ ybuf) {
  extern __shared__ __align__(16) char smem[];
  u16*   Hs   = (u16*)smem;                  // [64][64][8]  64 KB (h1/h2)
  u16*   Axf  = (u16*)smem;                  // [32][64][8]  32 KB (aliased)
  u16*   WstA = (u16*)(smem + 65536);        // 32 KB
  u16*   WstB = (u16*)(smem + 98304);        // 32 KB
  float* redS = (float*)(smem + 131072);     // 4 KB [64][16]
  float* redQ = (float*)(smem + 135168);     // 4 KB
  int*   sTok = (int*)(smem + 139264);       // 256 B

  const int t = threadIdx.x, lane = t & 63, wv = t >> 6;   // wv 0..15
  const int cl = lane & 15, qd = lane >> 4;
  // XCD-chunked swizzle (gridDim.x == 4104 == 8*513, bijective)
  const int cpx = gridDim.x >> 3;
  const int blk = (blockIdx.x & 7) * cpx + (blockIdx.x >> 3);
  const int r0 = blk * 64;

  int e = 0;
#pragma unroll
  for (int i = 1; i < 8; ++i) if (r0 >= off[i]) e = i;
  if (r0 >= off[8]) return;
  const int end = off[e] + counts[e];

  if (t < 64) {
    int slot = r0 + t;
    sTok[t] = (slot < end) ? perm[slot] : 0;
  }
  WAITLGKM0;
  BAR();

  const u16* W1e = W1i + (size_t)e * (8 * 2048 * 8);
  const u16* W2e = W2i + (size_t)e * (16 * 2048 * 8);
  const u16* W3e = W3i + (size_t)e * (16 * 1024 * 8);

  // gather x rows -> Axf (2 VMEM / thread), dest linear per wave
  {
    const int m = t & 63;
    const u16* src = xb + (size_t)sTok[m] * 256;
#pragma unroll
    for (int i = 0; i < 2; ++i) {
      int c = (t >> 6) + i * 16;                // 0..31 (wave-uniform)
      gload16(src + c * 8, Axf + (size_t)(c * 64 + m) * 8);
    }
  }
  // prologue: W1 tile 0 -> WstA (2 VMEM / thread)
  stage32(W1e, WstA, t);

  floatx4 acc[4][2];
#pragma unroll
  for (int rt = 0; rt < 4; ++rt)
#pragma unroll
    for (int c = 0; c < 2; ++c) acc[rt][c] = (floatx4){0.f, 0.f, 0.f, 0.f};

  // ---- GEMM1: K=256 (8 k-tiles); wave covers 64 rows x 32 cols ----
#pragma unroll 2
  for (int kt = 0; kt < 8; ++kt) {
    u16* cur = (kt & 1) ? WstB : WstA;
    u16* nxt = (kt & 1) ? WstA : WstB;
    if (kt < 7) stage32(W1e + (size_t)(kt + 1) * (2048 * 8), nxt, t);
    else        stage32(W2e, nxt, t);           // prefetch GEMM2 tile 0
    WAITVM(2);                                  // cur staged; next 2 in flight
    BAR();
    short8 a[4];
#pragma unroll
    for (int rt = 0; rt < 4; ++rt)
      a[rt] = *(const short8*)(Axf + ((size_t)(kt * 4 + qd) * 64 + rt * 16 + cl) * 8);
#pragma unroll
    for (int c = 0; c < 2; ++c) {
      short8 bb = *(const short8*)(cur + ((size_t)qd * 512 + wv * 32 + c * 16 + cl) * 8);
#pragma unroll
      for (int rt = 0; rt < 4; ++rt)
        acc[rt][c] = __builtin_amdgcn_mfma_f32_16x16x32_bf16(a[rt], bb, acc[rt][c], 0, 0, 0);
    }
    WAITLGKM0;                                  // my ds_reads of cur done
    BAR();                                      // all waves done -> nxt-overwrite safe
  }
  ln_gelu_epi16(acc, b1 + e * D_HID, g1 + e * D_HID, be1 + e * D_HID,
                Hs, redS, redQ, wv, cl, qd);    // W2 tile0 flies underneath

#pragma unroll
  for (int rt = 0; rt < 4; ++rt)
#pragma unroll
    for (int c = 0; c < 2; ++c) acc[rt][c] = (floatx4){0.f, 0.f, 0.f, 0.f};

  // ---- GEMM2: K=512 (16 k-tiles), A = h1 from LDS ----
#pragma unroll 2
  for (int kt = 0; kt < 16; ++kt) {
    u16* cur = (kt & 1) ? WstB : WstA;
    u16* nxt = (kt & 1) ? WstA : WstB;
    if (kt < 15) { stage32(W2e + (size_t)(kt + 1) * (2048 * 8), nxt, t); WAITVM(2); }
    else         { stage16(W3e, nxt, t);                                 WAITVM(1); }
    BAR();
    short8 a[4];
#pragma unroll
    for (int rt = 0; rt < 4; ++rt)
      a[rt] = *(const short8*)(Hs + ((size_t)(kt * 4 + qd) * 64 + rt * 16 + cl) * 8);
#pragma unroll
    for (int c = 0; c < 2; ++c) {
      short8 bb = *(const short8*)(cur + ((size_t)qd * 512 + wv * 32 + c * 16 + cl) * 8);
#pragma unroll
      for (int rt = 0; rt < 4; ++rt)
        acc[rt][c] = __builtin_amdgcn_mfma_f32_16x16x32_bf16(a[rt], bb, acc[rt][c], 0, 0, 0);
    }
    WAITLGKM0;
    BAR();
  }
  ln_gelu_epi16(acc, b2 + e * D_HID, g2 + e * D_HID, be2 + e * D_HID,
                Hs, redS, redQ, wv, cl, qd);    // W3 tile0 flies underneath

  // ---- GEMM3: K=512, N=256; wave covers 64 rows x 16 cols ----
  floatx4 acc3[4];
#pragma unroll
  for (int rt = 0; rt < 4; ++rt) acc3[rt] = (floatx4){0.f, 0.f, 0.f, 0.f};

#pragma unroll 2
  for (int kt = 0; kt < 16; ++kt) {
    u16* cur = (kt & 1) ? WstB : WstA;
    u16* nxt = (kt & 1) ? WstA : WstB;
    if (kt < 15) { stage16(W3e + (size_t)(kt + 1) * (1024 * 8), nxt, t); WAITVM(1); }
    else         { WAITVM(0); }
    BAR();
    short8 a[4];
#pragma unroll
    for (int rt = 0; rt < 4; ++rt)
      a[rt] = *(const short8*)(Hs + ((size_t)(kt * 4 + qd) * 64 + rt * 16 + cl) * 8);
    short8 bb = *(const short8*)(cur + ((size_t)qd * 256 + wv * 16 + cl) * 8);
#pragma unroll
    for (int rt = 0; rt < 4; ++rt)
      acc3[rt] = __builtin_amdgcn_mfma_f32_16x16x32_bf16(a[rt], bb, acc3[rt], 0, 0, 0);
    WAITLGKM0;
    BAR();
  }

  // epilogue 3: y = acc + b3 -> bf16 tile in LDS (WstA is free now),
  // then one coalesced dwordx4 sweep to ybuf (2 stores/thread, 16B each).
  // Padding rows (>= end) carry garbage but their slots are never read.
  {
    float b3v = b3[e * D_OUTP + wv * 16 + cl];
    u16* yl = WstA;                            // [64 rows][256 cols] bf16, 32 KB
#pragma unroll
    for (int rt = 0; rt < 4; ++rt)
#pragma unroll
      for (int r = 0; r < 4; ++r) {
        int row = rt * 16 + qd * 4 + r;
        yl[row * 256 + wv * 16 + cl] = f2bf(acc3[rt][r] + b3v);
      }
    WAITLGKM0;
    BAR();
    const uint4* src4 = (const uint4*)yl;
    uint4* dst4 = (uint4*)(ybuf + (size_t)r0 * 256);
#pragma unroll
    for (int i = 0; i < 2; ++i) dst4[t + i * 1024] = src4[t + i * 1024];
  }
}

// ---------------------------------------------------------------------------
// Combine: out[t] = w1*y[slot(t,0)] + w2*y[slot(t,1)]. One wave per token.
// ---------------------------------------------------------------------------
__global__ __launch_bounds__(256) void combine_k(
    const u16* __restrict__ ybuf, const int* __restrict__ islot,
    const float2* __restrict__ wts, float* __restrict__ out) {
  const int lane  = threadIdx.x & 63;
  const int token = blockIdx.x * 4 + (threadIdx.x >> 6);
  const int s0 = islot[token * 2 + 0];
  const int s1 = islot[token * 2 + 1];
  const float2 w = wts[token];
  ushort4 ya = *(const ushort4*)(ybuf + (size_t)s0 * 256 + lane * 4);
  ushort4 yb = *(const ushort4*)(ybuf + (size_t)s1 * 256 + lane * 4);
  float4 o;
  o.x = w.x * bf2f(ya.x) + w.y * bf2f(yb.x);
  o.y = w.x * bf2f(ya.y) + w.y * bf2f(yb.y);
  o.z = w.x * bf2f(ya.z) + w.y * bf2f(yb.z);
  o.w = w.x * bf2f(ya.w) + w.y * bf2f(yb.w);
  ((float4*)(out + (size_t)token * D_OUTP))[lane] = o;
}

// ---------------------------------------------------------------------------
// Launcher. ws layout (bytes):
//   xb    @ 0         : 67,108,864
//   W1img @ 67108864  : 2,097,152
//   W2img @ 69206016  : 4,194,304
//   W3img @ 73400320  : 2,097,152
//   tope  @ 75497472  : 1,048,576
//   wts   @ 76546048  : 1,048,576
//   perm  @ 77594624  : 1,051,648
//   islot @ 78646272  : 1,048,576
//   meta  @ 79694848  : 128      (counts[8] | cursors[8] | off[9])
//   ybuf  @ 79695872  : 134,610,944  (262912 slots x 256 x bf16)
//   total ~214.3 MB
// ---------------------------------------------------------------------------
extern "C" void kernel_launch(void* const* d_in, const int* in_sizes, int n_in,
                              void* d_out, int out_size, void* d_ws,
                              size_t ws_size, hipStream_t stream) {
  const float* x   = (const float*)d_in[0];
  const float* gw1 = (const float*)d_in[1];
  const float* gw2 = (const float*)d_in[2];
  const float* W1  = (const float*)d_in[3];
  const float* b1  = (const float*)d_in[4];
  const float* g1  = (const float*)d_in[5];
  const float* be1 = (const float*)d_in[6];
  const float* W2  = (const float*)d_in[7];
  const float* b2  = (const float*)d_in[8];
  const float* g2  = (const float*)d_in[9];
  const float* be2 = (const float*)d_in[10];
  const float* W3  = (const float*)d_in[11];
  const float* b3  = (const float*)d_in[12];
  float* out = (float*)d_out;

  char* ws = (char*)d_ws;
  u16*    xb    = (u16*)(ws);
  u16*    W1i   = (u16*)(ws + 67108864);
  u16*    W2i   = (u16*)(ws + 69206016);
  u16*    W3i   = (u16*)(ws + 73400320);
  int2*   tope  = (int2*)(ws + 75497472);
  float2* wtsp  = (float2*)(ws + 76546048);
  int*    perm  = (int*)(ws + 77594624);
  int*    islot = (int*)(ws + 78646272);
  int*    meta  = (int*)(ws + 79694848);
  u16*    ybuf  = (u16*)(ws + 79695872);
  int* counts  = meta;        // 8
  int* cursors = meta + 8;    // 8
  int* off     = meta + 16;   // 9

  static const int LDS_BYTES = 139520;
  hipFuncSetAttribute((const void*)moe_fused,
                      hipFuncAttributeMaxDynamicSharedMemorySize, LDS_BYTES);

  hipMemsetAsync(meta, 0, 128, stream);

  gate_cast<<<N_TOK / 4, 256, 0, stream>>>(x, gw1, gw2, xb, tope, wtsp);
  count_k<<<N_TOK / 256, 256, 0, stream>>>(tope, counts);
  scan_k<<<1, 64, 0, stream>>>(counts, off);
  assign_k<<<N_TOK / 256, 256, 0, stream>>>(tope, off, cursors, perm, islot);

  wprep<512><<<dim3(8, 1, 8), 256, 0, stream>>>(W1, W1i, 256);
  wprep<512><<<dim3(16, 1, 8), 256, 0, stream>>>(W2, W2i, 512);
  wprep<256><<<dim3(16, 1, 8), 256, 0, stream>>>(W3, W3i, 512);

  const int nblk = (2 * N_TOK + NEXP * 63 + 63) / 64;   // 4104
  moe_fused<<<nblk, 1024, LDS_BYTES, stream>>>(
      xb, W1i, W2i, W3i, b1, g1, be1, b2, g2, be2, b3,
      off, counts, perm, ybuf);

  combine_k<<<N_TOK / 4, 256, 0, stream>>>(ybuf, islot, wtsp, out);
}

// Round 10
// 1807.258 us; speedup vs baseline: 1.5415x; 1.5415x over previous
//
// moe_fused v8: v6 (908us) + branchless A&S-7.1.26 erf GELU (epilogue VALU cut)
#include <hip/hip_runtime.h>

#define N_TOK 131072
#define D_INP 256
#define D_HID 512
#define D_OUTP 256
#define NEXP 8

typedef unsigned short u16;
using short8  = __attribute__((ext_vector_type(8))) short;
using floatx4 = __attribute__((ext_vector_type(4))) float;

#define WAITVM(N) asm volatile("s_waitcnt vmcnt(" #N ")" ::: "memory")
#define WAITLGKM0 asm volatile("s_waitcnt lgkmcnt(0)" ::: "memory")
#define BAR() __builtin_amdgcn_s_barrier()

static __device__ __forceinline__ u16 f2bf(float f) {
  unsigned u = __float_as_uint(f);
  u = (u + 0x7fffu + ((u >> 16) & 1u)) >> 16;   // round-to-nearest-even
  return (u16)u;
}
static __device__ __forceinline__ float bf2f(u16 u) {
  return __uint_as_float(((unsigned)u) << 16);
}
// GELU with branchless erf (Abramowitz-Stegun 7.1.26, |err| <= 1.5e-7):
// ~20 VALU instrs vs ~45+branches for ocml erff. Error is 2 orders below
// the bf16 rounding applied to h immediately after.
static __device__ __forceinline__ float gelu_exact(float v) {
  float x  = v * 0.70710678118654752f;
  float ax = fabsf(x);
  float t  = 1.0f / (1.0f + 0.3275911f * ax);
  float y  = t * (0.254829592f +
             t * (-0.284496736f +
             t * (1.421413741f +
             t * (-1.453152027f +
             t * 1.061405429f))));
  float er = 1.0f - y * __expf(-ax * ax);      // erf(|x|)
  er = copysignf(er, x);
  return 0.5f * v * (1.0f + er);
}
// async global->LDS, 16B per lane; dest must be wave-uniform base + lane*16
static __device__ __forceinline__ void gload16(const void* g, void* l) {
  __builtin_amdgcn_global_load_lds(
      (const __attribute__((address_space(1))) void*)g,
      (__attribute__((address_space(3))) void*)l, 16, 0, 0);
}
// stage a 32KB weight tile (4 VMEM instr / thread)
static __device__ __forceinline__ void stageW4(const u16* wsrc, u16* dst, int t) {
#pragma unroll
  for (int i = 0; i < 4; ++i) {
    int idx = t + i * 512;
    gload16(wsrc + (size_t)idx * 8, dst + (size_t)idx * 8);
  }
}
// stage a 16KB weight tile (2 VMEM instr / thread)
static __device__ __forceinline__ void stageW2(const u16* wsrc, u16* dst, int t) {
#pragma unroll
  for (int i = 0; i < 2; ++i) {
    int idx = t + i * 512;
    gload16(wsrc + (size_t)idx * 8, dst + (size_t)idx * 8);
  }
}

// ---------------------------------------------------------------------------
// Gating: one wave per token. logits = tanh(x@gw1) @ gw2 ; softmax ; top-2 ;
// renormalize. Writes (e1,e2) + (w1,w2) per token. Also casts x -> bf16.
// ---------------------------------------------------------------------------
__global__ __launch_bounds__(256) void gate_cast(
    const float* __restrict__ x, const float* __restrict__ gw1,
    const float* __restrict__ gw2, u16* __restrict__ xb,
    int2* __restrict__ tope, float2* __restrict__ wts) {
  const int lane  = threadIdx.x & 63;
  const int token = blockIdx.x * 4 + (threadIdx.x >> 6);

  const float4 v = ((const float4*)(x + (size_t)token * D_INP))[lane];

  ushort4 b4;
  b4.x = f2bf(v.x); b4.y = f2bf(v.y); b4.z = f2bf(v.z); b4.w = f2bf(v.w);
  *(ushort4*)(xb + (size_t)token * D_INP + lane * 4) = b4;

  float p[16];
#pragma unroll
  for (int j = 0; j < 16; ++j) p[j] = 0.f;
  const float va[4] = {v.x, v.y, v.z, v.w};
  const int d0 = lane * 4;
#pragma unroll
  for (int r = 0; r < 4; ++r) {
    const float xr = va[r];
    const float4* g4 = (const float4*)(gw1 + (size_t)(d0 + r) * 16);
    float4 a0 = g4[0], a1 = g4[1], a2 = g4[2], a3 = g4[3];
    p[0]  += xr * a0.x; p[1]  += xr * a0.y; p[2]  += xr * a0.z; p[3]  += xr * a0.w;
    p[4]  += xr * a1.x; p[5]  += xr * a1.y; p[6]  += xr * a1.z; p[7]  += xr * a1.w;
    p[8]  += xr * a2.x; p[9]  += xr * a2.y; p[10] += xr * a2.z; p[11] += xr * a2.w;
    p[12] += xr * a3.x; p[13] += xr * a3.y; p[14] += xr * a3.z; p[15] += xr * a3.w;
  }
#pragma unroll
  for (int m = 1; m < 64; m <<= 1) {
#pragma unroll
    for (int j = 0; j < 16; ++j) p[j] += __shfl_xor(p[j], m, 64);
  }
  float tj[16];
#pragma unroll
  for (int j = 0; j < 16; ++j) tj[j] = tanhf(p[j]);

  float lg[8];
#pragma unroll
  for (int e = 0; e < 8; ++e) {
    float s = 0.f;
#pragma unroll
    for (int j = 0; j < 16; ++j) s += tj[j] * gw2[j * 8 + e];
    lg[e] = s;
  }
  float mx = lg[0];
#pragma unroll
  for (int e = 1; e < 8; ++e) mx = fmaxf(mx, lg[e]);
  float ex[8], se = 0.f;
#pragma unroll
  for (int e = 0; e < 8; ++e) { ex[e] = expf(lg[e] - mx); se += ex[e]; }
  float inv = 1.f / se;
#pragma unroll
  for (int e = 0; e < 8; ++e) ex[e] *= inv;
  int i1 = 0; float v1 = ex[0];
#pragma unroll
  for (int e = 1; e < 8; ++e) if (ex[e] > v1) { v1 = ex[e]; i1 = e; }
  int i2 = -1; float v2 = -1.f;
#pragma unroll
  for (int e = 0; e < 8; ++e) if (e != i1 && ex[e] > v2) { v2 = ex[e]; i2 = e; }
  float rs = 1.f / (v1 + v2 + 1e-12f);

  if (lane == 0) {
    tope[token] = make_int2(i1, i2);
    wts[token]  = make_float2(v1 * rs, v2 * rs);
  }
}

// ---------------------------------------------------------------------------
// Routing: count per-expert (wave-aggregated), scan (padded to 64), assign.
// ---------------------------------------------------------------------------
__global__ __launch_bounds__(256) void count_k(const int2* __restrict__ tope,
                                               int* __restrict__ counts) {
  int t = blockIdx.x * 256 + threadIdx.x;
  int lane = threadIdx.x & 63;
  int2 ee = tope[t];
#pragma unroll
  for (int e = 0; e < 8; ++e) {
    unsigned long long m1 = __ballot(ee.x == e);
    unsigned long long m2 = __ballot(ee.y == e);
    int c = __popcll(m1) + __popcll(m2);
    if (lane == 0 && c) atomicAdd(counts + e, c);
  }
}

__global__ void scan_k(const int* __restrict__ counts, int* __restrict__ off) {
  if (threadIdx.x == 0 && blockIdx.x == 0) {
    int o = 0;
    for (int e = 0; e < 8; ++e) { off[e] = o; o += (counts[e] + 63) & ~63; }
    off[8] = o;
  }
}

__global__ __launch_bounds__(256) void assign_k(
    const int2* __restrict__ tope, const int* __restrict__ off,
    int* __restrict__ cursors, int* __restrict__ perm,
    int* __restrict__ islot) {
  int t = blockIdx.x * 256 + threadIdx.x;
  int lane = threadIdx.x & 63;
  int2 ee = tope[t];
  unsigned long long lt = (lane == 63) ? 0x7fffffffffffffffULL
                                       : ((1ULL << lane) - 1ULL);
#pragma unroll
  for (int k = 0; k < 2; ++k) {
    int e = k ? ee.y : ee.x;
#pragma unroll
    for (int q = 0; q < 8; ++q) {
      unsigned long long mask = __ballot(e == q);
      if (!mask) continue;
      int leader = __ffsll((long long)mask) - 1;
      int base = 0;
      if (lane == leader) base = atomicAdd(cursors + q, __popcll(mask));
      base = __shfl(base, leader);
      if (e == q) {
        int pos = base + __popcll(mask & lt);
        int slot = off[q] + pos;
        perm[slot] = t;
        islot[t * 2 + k] = slot;
      }
    }
  }
}

// ---------------------------------------------------------------------------
// Weight prep: W[e][k][n] fp32 -> LDS-image bf16 img[e][kt][q][n][8],
// element (k = kt*32 + q*8 + j, n). Staging then = pure linear copy.
// ---------------------------------------------------------------------------
template <int NW>
__global__ __launch_bounds__(256) void wprep(const float* __restrict__ W,
                                             u16* __restrict__ img, int K) {
  const int e = blockIdx.z, kt = blockIdx.x;
  const int chunks = 4 * NW;
  const float* Wp = W + (size_t)e * K * NW;
  u16* ip = img + ((size_t)e * (K / 32) + kt) * (size_t)chunks * 8;
  for (int idx = threadIdx.x; idx < chunks; idx += 256) {
    int q = idx / NW, n = idx % NW;
    int k0 = kt * 32 + q * 8;
    u16 tmp[8];
#pragma unroll
    for (int j = 0; j < 8; ++j) tmp[j] = f2bf(Wp[(size_t)(k0 + j) * NW + n]);
    *(uint4*)(ip + (size_t)idx * 8) = *(uint4*)tmp;
  }
}

// ---------------------------------------------------------------------------
// LN+GELU epilogue, register-lean: no mean/rstd arrays — mu/rsd recomputed
// per (rt,r) from the LDS reduction arrays inside the store loop (2 live
// scalars instead of 32). Raw barriers + lgkmcnt only — never drains vmcnt.
// ---------------------------------------------------------------------------
__device__ __forceinline__ void ln_gelu_epi(
    floatx4 (&acc)[4][4], const float* __restrict__ bias,
    const float* __restrict__ gam, const float* __restrict__ bet,
    u16* Hs, float* redS, float* redQ, int wv, int cl, int qd) {
#pragma unroll
  for (int c = 0; c < 4; ++c) {
    float bv = bias[wv * 64 + c * 16 + cl];
#pragma unroll
    for (int rt = 0; rt < 4; ++rt)
#pragma unroll
      for (int r = 0; r < 4; ++r) acc[rt][c][r] += bv;
  }
#pragma unroll
  for (int rt = 0; rt < 4; ++rt)
#pragma unroll
    for (int r = 0; r < 4; ++r) {
      float s = 0.f, q2 = 0.f;
#pragma unroll
      for (int c = 0; c < 4; ++c) { float v = acc[rt][c][r]; s += v; q2 += v * v; }
#pragma unroll
      for (int m = 1; m < 16; m <<= 1) {
        s += __shfl_xor(s, m, 64);
        q2 += __shfl_xor(q2, m, 64);
      }
      if (cl == 0) {
        int row = rt * 16 + qd * 4 + r;
        redS[row * 8 + wv] = s;
        redQ[row * 8 + wv] = q2;
      }
    }
  WAITLGKM0;
  BAR();
  // per-column constants (8 live VGPRs), then mu/rsd inline per (rt,r)
  float ga4[4], be4[4];
#pragma unroll
  for (int c = 0; c < 4; ++c) {
    int col = wv * 64 + c * 16 + cl;
    ga4[c] = gam[col];
    be4[c] = bet[col];
  }
#pragma unroll
  for (int rt = 0; rt < 4; ++rt)
#pragma unroll
    for (int r = 0; r < 4; ++r) {
      int row = rt * 16 + qd * 4 + r;
      float s = 0.f, q2 = 0.f;
#pragma unroll
      for (int w = 0; w < 8; ++w) { s += redS[row * 8 + w]; q2 += redQ[row * 8 + w]; }
      float mu = s * (1.f / 512.f);
      float rsd = rsqrtf(q2 * (1.f / 512.f) - mu * mu + 1e-5f);
#pragma unroll
      for (int c = 0; c < 4; ++c) {
        int col = wv * 64 + c * 16 + cl;
        int kt2 = col >> 5, q2i = (col >> 3) & 3, j = col & 7;
        float v = (acc[rt][c][r] - mu) * rsd * ga4[c] + be4[c];
        Hs[(((kt2 * 4 + q2i) * 64 + row) * 8) + j] = f2bf(gelu_exact(v));
      }
    }
  WAITLGKM0;
  BAR();
}

// ---------------------------------------------------------------------------
// Fused routed expert, double-buffered weight pipeline (counted vmcnt, raw
// barriers — vmcnt never drained to 0 inside the k-loops). Per 64-slot tile:
// x ->(GEMM1+LN+GELU)-> h1(LDS) ->(GEMM2+LN+GELU)-> h2(LDS, in place)
// ->(GEMM3+bias)-> y tile staged in LDS -> coalesced dwordx4 store to ybuf.
// waves_per_eu(2,2): LDS already caps at 1 block/CU = 2 waves/SIMD, so this
// pins the regalloc to the full 256-VGPR budget -> no scratch spills.
// LDS: Hs 64K (Axf aliased in first 32K) | WstA 32K | WstB 32K | red 4K | tok.
// ---------------------------------------------------------------------------
__global__ __attribute__((amdgpu_waves_per_eu(2, 2)))
__launch_bounds__(512) void moe_fused(
    const u16* __restrict__ xb, const u16* __restrict__ W1i,
    const u16* __restrict__ W2i, const u16* __restrict__ W3i,
    const float* __restrict__ b1, const float* __restrict__ g1,
    const float* __restrict__ be1, const float* __restrict__ b2,
    const float* __restrict__ g2, const float* __restrict__ be2,
    const float* __restrict__ b3, const int* __restrict__ off,
    const int* __restrict__ counts, const int* __restrict__ perm,
    u16* __restrict__ ybuf) {
  extern __shared__ __align__(16) char smem[];
  u16*   Hs   = (u16*)smem;                  // [16][4][64][8] 64 KB (h1/h2)
  u16*   Axf  = (u16*)smem;                  // [8][4][64][8]  32 KB (aliased)
  u16*   WstA = (u16*)(smem + 65536);        // 32 KB
  u16*   WstB = (u16*)(smem + 98304);        // 32 KB
  float* redS = (float*)(smem + 131072);     // 2 KB
  float* redQ = (float*)(smem + 133120);     // 2 KB
  int*   sTok = (int*)(smem + 135168);       // 256 B

  const int t = threadIdx.x, lane = t & 63, wv = t >> 6;
  const int cl = lane & 15, qd = lane >> 4;
  // XCD-chunked swizzle (gridDim.x == 4104 == 8*513, bijective)
  const int cpx = gridDim.x >> 3;
  const int blk = (blockIdx.x & 7) * cpx + (blockIdx.x >> 3);
  const int r0 = blk * 64;

  int e = 0;
#pragma unroll
  for (int i = 1; i < 8; ++i) if (r0 >= off[i]) e = i;
  if (r0 >= off[8]) return;
  const int end = off[e] + counts[e];

  if (t < 64) {
    int slot = r0 + t;
    sTok[t] = (slot < end) ? perm[slot] : 0;
  }
  WAITLGKM0;
  BAR();

  const u16* W1e = W1i + (size_t)e * (8 * 2048 * 8);
  const u16* W2e = W2i + (size_t)e * (16 * 2048 * 8);
  const u16* W3e = W3i + (size_t)e * (16 * 1024 * 8);

  // gather x rows -> Axf (4 VMEM / thread), dest linear in lane
  {
    const int m = t & 63;
    const u16* src = xb + (size_t)sTok[m] * 256;
#pragma unroll
    for (int i = 0; i < 4; ++i) {
      int c = (t >> 6) + i * 8;                 // 0..31
      gload16(src + c * 8, Axf + (size_t)(c * 64 + m) * 8);
    }
  }
  // prologue: W1 tile 0 -> WstA (4 VMEM / thread)
  stageW4(W1e, WstA, t);

  floatx4 acc[4][4];
#pragma unroll
  for (int rt = 0; rt < 4; ++rt)
#pragma unroll
    for (int c = 0; c < 4; ++c) acc[rt][c] = (floatx4){0.f, 0.f, 0.f, 0.f};

  // ---- GEMM1: K=256 (8 k-tiles) ----
#pragma unroll 2
  for (int kt = 0; kt < 8; ++kt) {
    u16* cur = (kt & 1) ? WstB : WstA;
    u16* nxt = (kt & 1) ? WstA : WstB;
    if (kt < 7) stageW4(W1e + (size_t)(kt + 1) * (2048 * 8), nxt, t);
    else        stageW4(W2e, nxt, t);           // prefetch GEMM2 tile 0
    WAITVM(4);                                  // cur staged; next 4 in flight
    BAR();
    short8 a[4];
#pragma unroll
    for (int rt = 0; rt < 4; ++rt)
      a[rt] = *(const short8*)(Axf + ((size_t)(kt * 4 + qd) * 64 + rt * 16 + cl) * 8);
#pragma unroll
    for (int c = 0; c < 4; ++c) {
      short8 bb = *(const short8*)(cur + ((size_t)qd * 512 + wv * 64 + c * 16 + cl) * 8);
#pragma unroll
      for (int rt = 0; rt < 4; ++rt)
        acc[rt][c] = __builtin_amdgcn_mfma_f32_16x16x32_bf16(a[rt], bb, acc[rt][c], 0, 0, 0);
    }
    WAITLGKM0;                                  // my ds_reads of cur done
    BAR();                                      // all waves done -> nxt-overwrite safe
  }
  ln_gelu_epi(acc, b1 + e * D_HID, g1 + e * D_HID, be1 + e * D_HID,
              Hs, redS, redQ, wv, cl, qd);      // W2 tile0 flies underneath

#pragma unroll
  for (int rt = 0; rt < 4; ++rt)
#pragma unroll
    for (int c = 0; c < 4; ++c) acc[rt][c] = (floatx4){0.f, 0.f, 0.f, 0.f};

  // ---- GEMM2: K=512 (16 k-tiles), A = h1 from LDS ----
#pragma unroll 2
  for (int kt = 0; kt < 16; ++kt) {
    u16* cur = (kt & 1) ? WstB : WstA;
    u16* nxt = (kt & 1) ? WstA : WstB;
    if (kt < 15) { stageW4(W2e + (size_t)(kt + 1) * (2048 * 8), nxt, t); WAITVM(4); }
    else         { stageW2(W3e, nxt, t);                                 WAITVM(2); }
    BAR();
    short8 a[4];
#pragma unroll
    for (int rt = 0; rt < 4; ++rt)
      a[rt] = *(const short8*)(Hs + ((size_t)(kt * 4 + qd) * 64 + rt * 16 + cl) * 8);
#pragma unroll
    for (int c = 0; c < 4; ++c) {
      short8 bb = *(const short8*)(cur + ((size_t)qd * 512 + wv * 64 + c * 16 + cl) * 8);
#pragma unroll
      for (int rt = 0; rt < 4; ++rt)
        acc[rt][c] = __builtin_amdgcn_mfma_f32_16x16x32_bf16(a[rt], bb, acc[rt][c], 0, 0, 0);
    }
    WAITLGKM0;
    BAR();
  }
  ln_gelu_epi(acc, b2 + e * D_HID, g2 + e * D_HID, be2 + e * D_HID,
              Hs, redS, redQ, wv, cl, qd);      // W3 tile0 flies underneath

  // ---- GEMM3: K=512, N=256; wave covers 64 rows x 32 cols ----
  floatx4 acc3[4][2];
#pragma unroll
  for (int rt = 0; rt < 4; ++rt)
#pragma unroll
    for (int c = 0; c < 2; ++c) acc3[rt][c] = (floatx4){0.f, 0.f, 0.f, 0.f};

#pragma unroll 2
  for (int kt = 0; kt < 16; ++kt) {
    u16* cur = (kt & 1) ? WstB : WstA;
    u16* nxt = (kt & 1) ? WstA : WstB;
    if (kt < 15) { stageW2(W3e + (size_t)(kt + 1) * (1024 * 8), nxt, t); WAITVM(2); }
    else         { WAITVM(0); }
    BAR();
    short8 a[4];
#pragma unroll
    for (int rt = 0; rt < 4; ++rt)
      a[rt] = *(const short8*)(Hs + ((size_t)(kt * 4 + qd) * 64 + rt * 16 + cl) * 8);
#pragma unroll
    for (int c = 0; c < 2; ++c) {
      short8 bb = *(const short8*)(cur + ((size_t)qd * 256 + wv * 32 + c * 16 + cl) * 8);
#pragma unroll
      for (int rt = 0; rt < 4; ++rt)
        acc3[rt][c] = __builtin_amdgcn_mfma_f32_16x16x32_bf16(a[rt], bb, acc3[rt][c], 0, 0, 0);
    }
    WAITLGKM0;
    BAR();
  }

  // epilogue 3: y = acc + b3 -> bf16 tile in LDS (WstA is free now),
  // then one coalesced dwordx4 sweep to ybuf (4 stores/thread, 16B each).
  // Padding rows (>= end) carry garbage but their slots are never read.
  {
    float b3v[2];
#pragma unroll
    for (int c = 0; c < 2; ++c) b3v[c] = b3[e * D_OUTP + wv * 32 + c * 16 + cl];
    u16* yl = WstA;                            // [64 rows][256 cols] bf16, 32 KB
#pragma unroll
    for (int rt = 0; rt < 4; ++rt)
#pragma unroll
      for (int r = 0; r < 4; ++r) {
        int row = rt * 16 + qd * 4 + r;
#pragma unroll
        for (int c = 0; c < 2; ++c)
          yl[row * 256 + wv * 32 + c * 16 + cl] = f2bf(acc3[rt][c][r] + b3v[c]);
      }
    WAITLGKM0;
    BAR();
    const uint4* src4 = (const uint4*)yl;
    uint4* dst4 = (uint4*)(ybuf + (size_t)r0 * 256);
#pragma unroll
    for (int i = 0; i < 4; ++i) dst4[t + i * 512] = src4[t + i * 512];
  }
}

// ---------------------------------------------------------------------------
// Combine: out[t] = w1*y[slot(t,0)] + w2*y[slot(t,1)]. One wave per token.
// ---------------------------------------------------------------------------
__global__ __launch_bounds__(256) void combine_k(
    const u16* __restrict__ ybuf, const int* __restrict__ islot,
    const float2* __restrict__ wts, float* __restrict__ out) {
  const int lane  = threadIdx.x & 63;
  const int token = blockIdx.x * 4 + (threadIdx.x >> 6);
  const int s0 = islot[token * 2 + 0];
  const int s1 = islot[token * 2 + 1];
  const float2 w = wts[token];
  ushort4 ya = *(const ushort4*)(ybuf + (size_t)s0 * 256 + lane * 4);
  ushort4 yb = *(const ushort4*)(ybuf + (size_t)s1 * 256 + lane * 4);
  float4 o;
  o.x = w.x * bf2f(ya.x) + w.y * bf2f(yb.x);
  o.y = w.x * bf2f(ya.y) + w.y * bf2f(yb.y);
  o.z = w.x * bf2f(ya.z) + w.y * bf2f(yb.z);
  o.w = w.x * bf2f(ya.w) + w.y * bf2f(yb.w);
  ((float4*)(out + (size_t)token * D_OUTP))[lane] = o;
}

// ---------------------------------------------------------------------------
// Launcher. ws layout (bytes):
//   xb    @ 0         : 67,108,864
//   W1img @ 67108864  : 2,097,152
//   W2img @ 69206016  : 4,194,304
//   W3img @ 73400320  : 2,097,152
//   tope  @ 75497472  : 1,048,576
//   wts   @ 76546048  : 1,048,576
//   perm  @ 77594624  : 1,051,648
//   islot @ 78646272  : 1,048,576
//   meta  @ 79694848  : 128      (counts[8] | cursors[8] | off[9])
//   ybuf  @ 79695872  : 134,610,944  (262912 slots x 256 x bf16)
//   total ~214.3 MB
// ---------------------------------------------------------------------------
extern "C" void kernel_launch(void* const* d_in, const int* in_sizes, int n_in,
                              void* d_out, int out_size, void* d_ws,
                              size_t ws_size, hipStream_t stream) {
  const float* x   = (const float*)d_in[0];
  const float* gw1 = (const float*)d_in[1];
  const float* gw2 = (const float*)d_in[2];
  const float* W1  = (const float*)d_in[3];
  const float* b1  = (const float*)d_in[4];
  const float* g1  = (const float*)d_in[5];
  const float* be1 = (const float*)d_in[6];
  const float* W2  = (const float*)d_in[7];
  const float* b2  = (const float*)d_in[8];
  const float* g2  = (const float*)d_in[9];
  const float* be2 = (const float*)d_in[10];
  const float* W3  = (const float*)d_in[11];
  const float* b3  = (const float*)d_in[12];
  float* out = (float*)d_out;

  char* ws = (char*)d_ws;
  u16*    xb    = (u16*)(ws);
  u16*    W1i   = (u16*)(ws + 67108864);
  u16*    W2i   = (u16*)(ws + 69206016);
  u16*    W3i   = (u16*)(ws + 73400320);
  int2*   tope  = (int2*)(ws + 75497472);
  float2* wtsp  = (float2*)(ws + 76546048);
  int*    perm  = (int*)(ws + 77594624);
  int*    islot = (int*)(ws + 78646272);
  int*    meta  = (int*)(ws + 79694848);
  u16*    ybuf  = (u16*)(ws + 79695872);
  int* counts  = meta;        // 8
  int* cursors = meta + 8;    // 8
  int* off     = meta + 16;   // 9

  static const int LDS_BYTES = 135424;
  hipFuncSetAttribute((const void*)moe_fused,
                      hipFuncAttributeMaxDynamicSharedMemorySize, LDS_BYTES);

  hipMemsetAsync(meta, 0, 128, stream);

  gate_cast<<<N_TOK / 4, 256, 0, stream>>>(x, gw1, gw2, xb, tope, wtsp);
  count_k<<<N_TOK / 256, 256, 0, stream>>>(tope, counts);
  scan_k<<<1, 64, 0, stream>>>(counts, off);
  assign_k<<<N_TOK / 256, 256, 0, stream>>>(tope, off, cursors, perm, islot);

  wprep<512><<<dim3(8, 1, 8), 256, 0, stream>>>(W1, W1i, 256);
  wprep<512><<<dim3(16, 1, 8), 256, 0, stream>>>(W2, W2i, 512);
  wprep<256><<<dim3(16, 1, 8), 256, 0, stream>>>(W3, W3i, 512);

  const int nblk = (2 * N_TOK + NEXP * 63 + 63) / 64;   // 4104
  moe_fused<<<nblk, 512, LDS_BYTES, stream>>>(
      xb, W1i, W2i, W3i, b1, g1, be1, b2, g2, be2, b3,
      off, counts, perm, ybuf);

  combine_k<<<N_TOK / 4, 256, 0, stream>>>(ybuf, islot, wtsp, out);
}